// Round 10
// baseline (251.813 us; speedup 1.0000x reference)
//
#include <hip/hip_runtime.h>

// GCN encoder, N=50000, E=800000.
// R10: gather edge-segments split across LANE PAIRS (lanes 2k/2k+1 take
// alternating 4-edge blocks -> 8 independent 16B row loads in flight per
// pair, half-length dependent chains), combined with 8 shfl_xor adds.
// Single-variable test of "gathers are latency-bound" (R9's per-thread
// unroll underdelivered). All else carried from R9: MFMA bf16 GEMMs
// (LDS-free fragment-direct loads), sliced atomic-free CSR build, fused
// setup/convert kernel.

#define N_NODES 50000
#define F_IN    96
#define HIDDEN  128
#define OUT_F   64

typedef __attribute__((ext_vector_type(8))) short short8;
typedef __attribute__((ext_vector_type(4))) float floatx4;

__device__ inline unsigned short f2bf(float f) {          // RNE f32->bf16
    union { float f; unsigned u; } v; v.f = f;
    unsigned r = v.u + 0x7FFF + ((v.u >> 16) & 1);
    return (unsigned short)(r >> 16);
}
__device__ inline float bf2f(unsigned short b) {
    union { unsigned u; float f; } v; v.u = ((unsigned)b) << 16;
    return v.f;
}

// ---------------- setup: convert x + weights to bf16, zero deg/counter ------
__global__ __launch_bounds__(256) void setup_kernel(
    const float* __restrict__ x,
    const float* __restrict__ W1_rel, const float* __restrict__ W1_root,
    const float* __restrict__ W2_rel, const float* __restrict__ W2_root,
    unsigned short* __restrict__ xb, unsigned short* __restrict__ W1b,
    unsigned short* __restrict__ W2rb, unsigned short* __restrict__ W2sb,
    int* __restrict__ degz, int total8, int nzero)
{
    int i = blockIdx.x * 256 + threadIdx.x;
    if (i < total8) {
        const float4* p = (const float4*)(x + (size_t)i * 8);
        float4 v0 = p[0], v1 = p[1];
        short8 o;
        o[0] = (short)f2bf(v0.x); o[1] = (short)f2bf(v0.y);
        o[2] = (short)f2bf(v0.z); o[3] = (short)f2bf(v0.w);
        o[4] = (short)f2bf(v1.x); o[5] = (short)f2bf(v1.y);
        o[6] = (short)f2bf(v1.z); o[7] = (short)f2bf(v1.w);
        *(short8*)(xb + (size_t)i * 8) = o;
    }
    if (i < nzero) degz[i] = 0;
    if (i < 128 * 192) {
        int j = i / 192, k = i % 192;
        float v = (k < 96) ? W1_rel[j * 96 + k] : W1_root[j * 96 + k - 96];
        W1b[i] = f2bf(v);
    } else if (i < 128 * 192 + 64 * 128) {
        int i2 = i - 128 * 192;
        W2rb[i2] = f2bf(W2_rel[i2]);
    } else if (i < 128 * 192 + 2 * 64 * 128) {
        int i3 = i - 128 * 192 - 64 * 128;
        W2sb[i3] = f2bf(W2_root[i3]);
    }
}

// ---------------- CSR build ------------------------------------------------
__global__ __launch_bounds__(256) void deg_rank_kernel(
    const int* __restrict__ ei, int* __restrict__ deg,
    int* __restrict__ rank, int E)
{
    int i4 = blockIdx.x * 256 + threadIdx.x;
    int E4 = E >> 2;
    if (i4 < E4) {
        int4 s4 = ((const int4*)ei)[i4];
        int4 d4 = ((const int4*)(ei + E))[i4];
        int e0 = i4 * 4;
        int ss[4] = {s4.x, s4.y, s4.z, s4.w};
        int dd[4] = {d4.x, d4.y, d4.z, d4.w};
        #pragma unroll
        for (int k = 0; k < 4; ++k) {
            int s = ss[k], d = dd[k];
            if (s != d && (unsigned)d < (unsigned)N_NODES)
                rank[e0 + k] = atomicAdd(&deg[d], 1);
        }
    } else if (i4 == E4) {
        for (int e = E4 * 4; e < E; ++e) {
            int s = ei[e], d = ei[E + e];
            if (s != d && (unsigned)d < (unsigned)N_NODES)
                rank[e] = atomicAdd(&deg[d], 1);
        }
    }
}

__global__ __launch_bounds__(256) void alloc_kernel(
    const int* __restrict__ deg, int* __restrict__ off,
    int* __restrict__ counter, int N, int slice_size)
{
    int i = blockIdx.x * 256 + threadIdx.x;
    int lane = threadIdx.x & 63;
    int v = (i < N) ? deg[i] : 0;
    int s = v;
    #pragma unroll
    for (int d = 1; d < 64; d <<= 1) {
        int t = __shfl_up(s, d, 64);
        if (lane >= d) s += t;
    }
    int total = __shfl(s, 63, 64);
    int sl = (blockIdx.x * 256) / slice_size;
    int base = 0;
    if (lane == 63) base = atomicAdd(&counter[sl], total);
    base = __shfl(base, 63, 64);
    if (i < N) off[i] = base + s - v;
}

__global__ void scan8_kernel(const int* __restrict__ counter,
                             int* __restrict__ sbase)
{
    if (threadIdx.x == 0) {
        int run = 0;
        for (int s = 0; s < 8; ++s) { sbase[s] = run; run += counter[s]; }
    }
}

__global__ __launch_bounds__(256) void place_kernel(
    const int* __restrict__ ei, const int* __restrict__ off,
    const int* __restrict__ rank, const int* __restrict__ sbase,
    int* __restrict__ csr, int E, int slice_size)
{
    int sl = blockIdx.x & 7;
    int i4 = (blockIdx.x >> 3) * 256 + threadIdx.x;
    int sb = sbase[sl];
    int E4 = E >> 2;
    if (i4 < E4) {
        int4 d4 = ((const int4*)(ei + E))[i4];
        int e0 = i4 * 4;
        int dd[4] = {d4.x, d4.y, d4.z, d4.w};
        #pragma unroll
        for (int k = 0; k < 4; ++k) {
            int d = dd[k];
            if ((unsigned)d >= (unsigned)N_NODES) continue;
            if (d / slice_size != sl) continue;
            int e = e0 + k;
            int s = ei[e];
            if (s == d) continue;
            int p = sb + off[d] + rank[e];
            if ((unsigned)p < (unsigned)E)    // guard: invariant p < E
                csr[p] = s;
        }
    } else if (i4 == E4) {
        for (int e = E4 * 4; e < E; ++e) {
            int d = ei[E + e];
            if ((unsigned)d >= (unsigned)N_NODES) continue;
            if (d / slice_size != sl) continue;
            int s = ei[e];
            if (s == d) continue;
            int p = sb + off[d] + rank[e];
            if ((unsigned)p < (unsigned)E)
                csr[p] = s;
        }
    }
}

// ---------------- gather (bf16): agg[n] = sum feat[src] ----------------------
// Lane-pair split: lanes 2k/2k+1 take alternating 4-edge blocks of one
// (node, chunk) segment; partial sums combined via shfl_xor(1).
template<int F>
__global__ __launch_bounds__(256) void gather_agg_bf(
    const unsigned short* __restrict__ feat, const int* __restrict__ off,
    const int* __restrict__ deg, const int* __restrict__ sbase,
    const int* __restrict__ csr, unsigned short* __restrict__ agg,
    int N, int E, int slice_size)
{
    constexpr int C = F / 8;
    int gid = blockIdx.x * 256 + threadIdx.x;
    int pairid = gid >> 1;
    int half = gid & 1;
    int node = pairid / C;
    int c = pairid % C;
    if (node >= N) return;                    // both halves exit together
    int j0 = sbase[node / slice_size] + off[node];
    int end = j0 + deg[node];
    if (j0 < 0) j0 = 0;                       // guards (no-ops when sane)
    if (end > E) end = E;
    float acc[8] = {};
    const unsigned short* fc = feat + c * 8;
    int j = j0 + half * 4;
    while (j < end) {
        if (j + 3 < end) {                    // full 4-block
            int s0 = csr[j], s1 = csr[j + 1], s2 = csr[j + 2], s3 = csr[j + 3];
            short8 v0 = *(const short8*)(fc + (size_t)s0 * F);
            short8 v1 = *(const short8*)(fc + (size_t)s1 * F);
            short8 v2 = *(const short8*)(fc + (size_t)s2 * F);
            short8 v3 = *(const short8*)(fc + (size_t)s3 * F);
            #pragma unroll
            for (int i = 0; i < 8; ++i)
                acc[i] += (bf2f((unsigned short)v0[i]) + bf2f((unsigned short)v1[i]))
                        + (bf2f((unsigned short)v2[i]) + bf2f((unsigned short)v3[i]));
        } else {
            for (int jj = j; jj < end; ++jj) {
                int s0 = csr[jj];
                short8 v0 = *(const short8*)(fc + (size_t)s0 * F);
                #pragma unroll
                for (int i = 0; i < 8; ++i) acc[i] += bf2f((unsigned short)v0[i]);
            }
        }
        j += 8;                               // skip partner's block
    }
    #pragma unroll
    for (int i = 0; i < 8; ++i)               // combine lane pair
        acc[i] += __shfl_xor(acc[i], 1, 64);
    if (half == 0) {
        short8 o;
        #pragma unroll
        for (int i = 0; i < 8; ++i) o[i] = (short)f2bf(acc[i]);
        *(short8*)(agg + (size_t)node * F + c * 8) = o;
    }
}

// ---------------- MFMA GEMM: out = act(A@W^T + b [+ add]) --------------------
template<int KT, int NO, bool SPLIT, bool RELU, bool HAS_BIAS, bool HAS_ADD, bool OUT_BF>
__global__ __launch_bounds__(256) void gemm_mfma(
    const unsigned short* __restrict__ A1, const unsigned short* __restrict__ A2,
    const unsigned short* __restrict__ W, const float* __restrict__ bias,
    const unsigned short* __restrict__ addb, void* __restrict__ out, int N)
{
    constexpr int NC = KT / 32;
    const int lane = threadIdx.x & 63;
    const int wave = threadIdx.x >> 6;
    const int node_base = blockIdx.x * 64 + wave * 16;
    const int m = lane & 15, quad = lane >> 4;
    int na = node_base + m;
    if (na >= N) na = N - 1;                  // clamp: C rows >=N never stored
    short8 a[NC];
    #pragma unroll
    for (int c = 0; c < NC; ++c) {
        if (SPLIT) {
            constexpr int HK = KT / 2;
            if (c < NC / 2)
                a[c] = *(const short8*)(A1 + (size_t)na * HK + c * 32 + quad * 8);
            else
                a[c] = *(const short8*)(A2 + (size_t)na * HK + (c - NC / 2) * 32 + quad * 8);
        } else {
            a[c] = *(const short8*)(A1 + (size_t)na * KT + c * 32 + quad * 8);
        }
    }
    #pragma unroll
    for (int jt = 0; jt < NO / 16; ++jt) {
        floatx4 acc = {0.f, 0.f, 0.f, 0.f};
        const unsigned short* wb = W + (size_t)(jt * 16 + m) * KT + quad * 8;
        #pragma unroll
        for (int c = 0; c < NC; ++c) {
            short8 b = *(const short8*)(wb + c * 32);
            acc = __builtin_amdgcn_mfma_f32_16x16x32_bf16(a[c], b, acc, 0, 0, 0);
        }
        int col = jt * 16 + m;
        float bv = HAS_BIAS ? bias[col] : 0.f;
        #pragma unroll
        for (int r = 0; r < 4; ++r) {
            int node = node_base + quad * 4 + r;
            if (node < N) {
                float v = acc[r] + bv;
                if (HAS_ADD) v += bf2f(addb[(size_t)node * NO + col]);
                if (RELU) v = fmaxf(v, 0.f);
                if (OUT_BF) ((unsigned short*)out)[(size_t)node * NO + col] = f2bf(v);
                else        ((float*)out)[(size_t)node * NO + col] = v;
            }
        }
    }
}

extern "C" void kernel_launch(void* const* d_in, const int* in_sizes, int n_in,
                              void* d_out, int out_size, void* d_ws, size_t ws_size,
                              hipStream_t stream) {
    const float* x       = (const float*)d_in[0];
    const int*   ei      = (const int*)d_in[1];
    const float* W1_rel  = (const float*)d_in[2];
    const float* b1      = (const float*)d_in[3];
    const float* W1_root = (const float*)d_in[4];
    const float* W2_rel  = (const float*)d_in[5];
    const float* b2      = (const float*)d_in[6];
    const float* W2_root = (const float*)d_in[7];
    float* out = (float*)d_out;

    const int N = in_sizes[0] / F_IN;       // 50000
    const int E = in_sizes[1] / 2;          // 800000
    const int slice_size = ((N + 2047) / 2048) * 256;

    // Workspace (~52 MB):
    char* ws = (char*)d_ws;
    size_t p = 0;
    unsigned short* xb    = (unsigned short*)(ws + p); p += (size_t)N_NODES * F_IN * 2;
    unsigned short* agg1b = (unsigned short*)(ws + p); p += (size_t)N_NODES * F_IN * 2;
    unsigned short* h     = (unsigned short*)(ws + p); p += (size_t)N_NODES * HIDDEN * 2;
    unsigned short* t     = (unsigned short*)(ws + p); p += (size_t)N_NODES * OUT_F * 2;
    unsigned short* agg2b = (unsigned short*)(ws + p); p += (size_t)N_NODES * OUT_F * 2;
    unsigned short* W1b   = (unsigned short*)(ws + p); p += (size_t)128 * 192 * 2;
    unsigned short* W2rb  = (unsigned short*)(ws + p); p += (size_t)64 * 128 * 2;
    unsigned short* W2sb  = (unsigned short*)(ws + p); p += (size_t)64 * 128 * 2;
    int* deg     = (int*)(ws + p);  p += (size_t)N_NODES * 4;
    int* counter = (int*)(ws + p);  p += 8 * 4;         // contiguous with deg
    int* off     = (int*)(ws + p);  p += (size_t)N_NODES * 4;
    int* sbase   = (int*)(ws + p);  p += 8 * 4;
    int* rank    = (int*)(ws + p);  p += (size_t)800000 * 4;
    int* csr     = (int*)(ws + p);

    // ---- setup (convert + zero) and CSR build ----
    {
        int total8 = N * F_IN / 8;
        setup_kernel<<<(total8 + 255) / 256, 256, 0, stream>>>(
            x, W1_rel, W1_root, W2_rel, W2_root, xb, W1b, W2rb, W2sb,
            deg, total8, N + 8);
    }
    {
        int E4 = E >> 2;
        deg_rank_kernel<<<(E4 + 1 + 255) / 256, 256, 0, stream>>>(ei, deg, rank, E);
    }
    alloc_kernel<<<(N + 255) / 256, 256, 0, stream>>>(deg, off, counter, N, slice_size);
    scan8_kernel<<<1, 64, 0, stream>>>(counter, sbase);
    {
        int E4 = E >> 2;
        int bps = (E4 + 1 + 255) / 256;
        place_kernel<<<bps * 8, 256, 0, stream>>>(ei, off, rank, sbase, csr, E, slice_size);
    }

    const int gemm_blocks = (N + 63) / 64;

    // ---- layer 1: agg1 = segsum(xb); h = relu([agg1b|xb]@W1b^T + b1) --------
    {
        int total = N * (F_IN / 8) * 2;     // lane-pair split
        gather_agg_bf<F_IN><<<(total + 255) / 256, 256, 0, stream>>>(
            xb, off, deg, sbase, csr, agg1b, N, E, slice_size);
    }
    gemm_mfma<192, 128, true, true, true, false, true>
        <<<gemm_blocks, 256, 0, stream>>>(agg1b, xb, W1b, b1, nullptr, (void*)h, N);

    // ---- layer 2: t = h@W2rb^T; agg2 = segsum(t); out = h@W2sb^T + b2 + agg2
    gemm_mfma<128, 64, false, false, false, false, true>
        <<<gemm_blocks, 256, 0, stream>>>(h, nullptr, W2rb, nullptr, nullptr, (void*)t, N);
    {
        int total = N * (OUT_F / 8) * 2;    // lane-pair split
        gather_agg_bf<OUT_F><<<(total + 255) / 256, 256, 0, stream>>>(
            t, off, deg, sbase, csr, agg2b, N, E, slice_size);
    }
    gemm_mfma<128, 64, false, false, true, true, false>
        <<<gemm_blocks, 256, 0, stream>>>(h, nullptr, W2sb, b2, agg2b, (void*)out, N);
}